// Round 4
// baseline (377.067 us; speedup 1.0000x reference)
//
#include <hip/hip_runtime.h>
#include <math.h>

#define BB   128
#define SS   2048
#define DIN  1024
#define DSRC 1024
#define DOUT 1024
#define WW   64
#define WLEN 129
#define HH   512
#define WCH  17     // w-chunk per score block; 8 chunks cover 136 >= 129
#define GW   136    // gaussian table width (WLEN padded)

// counters (ints at OFF_CNT): [0]=fc1 done, [1]=merge done, [2..65]=gemm2c stripes, [66..193]=per-b score
#define CNT_FC1   0
#define CNT_MRG   1
#define CNT_G2    2
#define CNT_B     66

// workspace layout (bytes)
#define OFF_CNT   0           // 1024 B (256 ints)
#define OFF_WSI   1024
#define OFF_P     1536
#define OFF_LEN   2048
#define OFF_GTAB  4096        // float[128][136] -> ends 73728
#define OFF_XA    73728       // double[128][1024] = 1 MB
#define OFF_XB    1122304     // double[128][1024] = 1 MB
#define OFF_Z1P   2170880     // double[4][128][512] = 2 MB
#define OFF_OPIA  4268032     // float[128][1024]
#define OFF_OPIB  4792320     // float[128][1024]
#define OFF_CPART 5316608     // float[128][8][1024] = 4 MB
#define OFF_MPART 9510912
#define OFF_LPART 9515008
#define OFF_SPART 9519104     // float[128][8][17]
#define OFF_C32   9588736     // float[128][1024]
#define OFF_OPC   10113024    // float[4][128][1024] = 2 MB
#define WS_NEED   12210176

// d_out layout (floats)
#define DO_A    (BB*DOUT)        // 131072
#define DO_WS   (DO_A + BB*WLEN) // 147584
#define DO_WE   (DO_WS + BB)     // 147712

// ---------------- sync helpers (canonical release / acquire) ----------------
__device__ __forceinline__ void spin_wait(int* p, int target) {
    if (threadIdx.x == 0) {
        int guard = 0;
        while (atomicAdd(p, 0) < target && guard < (1 << 22)) {
            __builtin_amdgcn_s_sleep(8);
            ++guard;
        }
    }
    __syncthreads();
    __threadfence();            // acquire
}

// ---------------- GEMM core: 256 thr = 4 waves x 4 cols, lanes hold 2 rows ----------------
// A-chunk [128][64] staged to LDS [k][b] (+2 pad); register prefetch of next chunk.
template<int KRANGE>
__device__ __forceinline__ void gemm_core(
    const int t, const float* __restrict__ A, const int lda,
    const float* __restrict__ wbase, const int ldw,
    float* __restrict__ alds, double (&dac)[4][2])
{
    const int lane = t & 63;
    constexpr int NCH = KRANGE / 64;
    float4 pf[8];
    #pragma unroll
    for (int q = 0; q < 8; ++q) {
        const int f4 = t + 256*q;
        const int bb = f4 >> 4, c4 = f4 & 15;
        pf[q] = *reinterpret_cast<const float4*>(A + (size_t)bb*lda + c4*4);
    }
    for (int c = 0; c < NCH; ++c) {
        __syncthreads();
        #pragma unroll
        for (int q = 0; q < 8; ++q) {
            const int f4 = t + 256*q;
            const int bb = f4 >> 4, c4 = f4 & 15;
            alds[(c4*4+0)*130 + bb] = pf[q].x;
            alds[(c4*4+1)*130 + bb] = pf[q].y;
            alds[(c4*4+2)*130 + bb] = pf[q].z;
            alds[(c4*4+3)*130 + bb] = pf[q].w;
        }
        __syncthreads();
        if (c + 1 < NCH) {
            #pragma unroll
            for (int q = 0; q < 8; ++q) {
                const int f4 = t + 256*q;
                const int bb = f4 >> 4, c4 = f4 & 15;
                pf[q] = *reinterpret_cast<const float4*>(A + (size_t)bb*lda + (c+1)*64 + c4*4);
            }
        }
        const float* wr = wbase + c*64;
        #pragma unroll
        for (int kk16 = 0; kk16 < 64; kk16 += 16) {
            float fa[4][2];
            #pragma unroll
            for (int jj = 0; jj < 4; ++jj) { fa[jj][0] = 0.f; fa[jj][1] = 0.f; }
            #pragma unroll
            for (int kk = 0; kk < 16; ++kk) {
                const int k = kk16 + kk;
                const float2 av = *reinterpret_cast<const float2*>(&alds[k*130 + 2*lane]);
                #pragma unroll
                for (int jj = 0; jj < 4; ++jj) {
                    const float wvv = wr[jj*ldw + k];
                    fa[jj][0] = fmaf(wvv, av.x, fa[jj][0]);
                    fa[jj][1] = fmaf(wvv, av.y, fa[jj][1]);
                }
            }
            #pragma unroll
            for (int jj = 0; jj < 4; ++jj) {
                dac[jj][0] += (double)fa[jj][0];
                dac[jj][1] += (double)fa[jj][1];
            }
        }
    }
}

// variant staging (float)(xa+xb) from the two f64 x-partials (fc1). No prefetch (small K).
template<int KRANGE>
__device__ __forceinline__ void gemm_core_x(
    const int t, const double* __restrict__ xa, const double* __restrict__ xb,
    const int k0, const float* __restrict__ wbase, const int ldw,
    float* __restrict__ alds, double (&dac)[4][2])
{
    const int lane = t & 63;
    for (int c = 0; c < KRANGE/64; ++c) {
        __syncthreads();
        #pragma unroll
        for (int q = 0; q < 8; ++q) {
            const int f4 = t + 256*q;
            const int bb = f4 >> 4, c4 = f4 & 15;
            const size_t off = (size_t)bb*1024 + k0 + c*64 + c4*4;
            const double2 a0 = *reinterpret_cast<const double2*>(xa + off);
            const double2 a1 = *reinterpret_cast<const double2*>(xa + off + 2);
            const double2 b0 = *reinterpret_cast<const double2*>(xb + off);
            const double2 b1 = *reinterpret_cast<const double2*>(xb + off + 2);
            alds[(c4*4+0)*130 + bb] = (float)(a0.x + b0.x);
            alds[(c4*4+1)*130 + bb] = (float)(a0.y + b0.y);
            alds[(c4*4+2)*130 + bb] = (float)(a1.x + b1.x);
            alds[(c4*4+3)*130 + bb] = (float)(a1.y + b1.y);
        }
        __syncthreads();
        const float* wr = wbase + c*64;
        #pragma unroll
        for (int kk16 = 0; kk16 < 64; kk16 += 16) {
            float fa[4][2];
            #pragma unroll
            for (int jj = 0; jj < 4; ++jj) { fa[jj][0] = 0.f; fa[jj][1] = 0.f; }
            #pragma unroll
            for (int kk = 0; kk < 16; ++kk) {
                const int k = kk16 + kk;
                const float2 av = *reinterpret_cast<const float2*>(&alds[k*130 + 2*lane]);
                #pragma unroll
                for (int jj = 0; jj < 4; ++jj) {
                    const float wvv = wr[jj*ldw + k];
                    fa[jj][0] = fmaf(wvv, av.x, fa[jj][0]);
                    fa[jj][1] = fmaf(wvv, av.y, fa[jj][1]);
                }
            }
            #pragma unroll
            for (int jj = 0; jj < 4; ++jj) {
                dac[jj][0] += (double)fa[jj][0];
                dac[jj][1] += (double)fa[jj][1];
            }
        }
    }
}

// ---------------- L1: combo = gemm1(split2 -> xa/xb f64) | gemm2i(split2 -> opia/b) | lengths | cnt init
__global__ __launch_bounds__(256)
void k_combo(const float* __restrict__ input, const float* __restrict__ Wi,
             const float* __restrict__ Wo, const unsigned char* __restrict__ mask,
             double* __restrict__ xa, double* __restrict__ xb,
             float* __restrict__ opia, float* __restrict__ opib,
             int* __restrict__ lengths, int* __restrict__ cnt)
{
    __shared__ __align__(16) float alds[64*130];
    const int blk = blockIdx.x, t = threadIdx.x;
    const int lane = t & 63;
    const int wvid = __builtin_amdgcn_readfirstlane(t >> 6);

    double dac[4][2];
    #pragma unroll
    for (int jj = 0; jj < 4; ++jj) { dac[jj][0] = 0.0; dac[jj][1] = 0.0; }

    if (blk < 128) {
        // lengths prologue for b = blk
        {
            const int b = blk;
            const bool is_u8 = (mask[(size_t)SS*BB - 1] != 0);
            int c = 0;
            if (is_u8) {
                #pragma unroll
                for (int q = 0; q < 8; ++q)
                    c += (mask[(size_t)(t + 256*q)*BB + b] != 0) ? 1 : 0;
            } else {
                const int* m32 = (const int*)mask;
                #pragma unroll
                for (int q = 0; q < 8; ++q)
                    c += (m32[(size_t)(t + 256*q)*BB + b] != 0) ? 1 : 0;
            }
            int* red = (int*)alds;
            red[t] = c;
            __syncthreads();
            for (int st = 128; st >= 1; st >>= 1) {
                if (t < st) red[t] += red[t + st];
                __syncthreads();
            }
            if (t == 0) lengths[b] = SS - red[0];
        }
        // gemm1: x half = input @ Wi^T
        const int jb = blk & 63, ks = blk >> 6;
        const int j0 = jb*16 + wvid*4;
        gemm_core<512>(t, input + ks*512, DIN, Wi + (size_t)j0*DIN + ks*512, DIN, alds, dac);
        double* dst = ks ? xb : xa;
        #pragma unroll
        for (int i = 0; i < 2; ++i) {
            const int b = 2*lane + i;
            #pragma unroll
            for (int jj = 0; jj < 4; ++jj) dst[(size_t)b*DSRC + j0 + jj] = dac[jj][i];
        }
    } else {
        if (t < 2) cnt[(blk - 128)*2 + t] = 0;   // zero 256 counter ints across the 128 blocks
        // gemm2i: op input-half = input @ Wo[:,1024:]^T
        const int g = blk - 128;
        const int jb = g & 63, ks = g >> 6;
        const int j0 = jb*16 + wvid*4;
        gemm_core<512>(t, input + ks*512, DIN, Wo + (size_t)j0*(DIN+DSRC) + 1024 + ks*512,
                       DIN + DSRC, alds, dac);
        float* dst = ks ? opib : opia;
        #pragma unroll
        for (int i = 0; i < 2; ++i) {
            const int b = 2*lane + i;
            #pragma unroll
            for (int jj = 0; jj < 4; ++jj) dst[(size_t)b*DOUT + j0 + jj] = (float)dac[jj][i];
        }
    }
}

// ---------------- L2: fc1 (128 worker blocks, split4) + fc2 (32 spinner blocks) ----------------
__global__ __launch_bounds__(256)
void k_fc12(const double* __restrict__ xa, const double* __restrict__ xb,
            const float* __restrict__ W1, const float* __restrict__ b1,
            const float* __restrict__ W2f, const float* __restrict__ b2,
            const int* __restrict__ lengths, double* __restrict__ z1p,
            int* __restrict__ wsi, float* __restrict__ pbuf,
            float* __restrict__ gtab, float* __restrict__ dout, int* __restrict__ cnt)
{
    __shared__ __align__(16) float alds[64*130];
    const int blk = blockIdx.x, t = threadIdx.x;
    const int lane = t & 63;

    if (blk < 128) {
        const int wvid = __builtin_amdgcn_readfirstlane(t >> 6);
        const int jb = blk & 31, ks = blk >> 5;
        const int j0 = jb*16 + wvid*4;
        const int k0 = ks*256;
        double dac[4][2];
        #pragma unroll
        for (int jj = 0; jj < 4; ++jj) { dac[jj][0] = 0.0; dac[jj][1] = 0.0; }
        gemm_core_x<256>(t, xa, xb, k0, W1 + (size_t)j0*DIN + k0, DIN, alds, dac);
        #pragma unroll
        for (int i = 0; i < 2; ++i) {
            const int b = 2*lane + i;
            #pragma unroll
            for (int jj = 0; jj < 4; ++jj)
                z1p[((size_t)ks*BB + b)*HH + j0 + jj] = dac[jj][i];
        }
        __threadfence();                   // release z1p
        __syncthreads();
        if (t == 0) atomicAdd(&cnt[CNT_FC1], 1);
    } else {
        spin_wait(&cnt[CNT_FC1], 128);
        const int sb = blk - 128;
        const int b = sb*4 + (t >> 6);
        double part = 0.0;
        #pragma unroll
        for (int q = 0; q < 8; ++q) {
            const int h = lane + 64*q;
            double z = 0.0;
            #pragma unroll
            for (int ks = 0; ks < 4; ++ks) z += z1p[((size_t)ks*BB + b)*HH + h];
            z += (double)b1[h];
            part += tanh(z) * (double)W2f[h];
        }
        #pragma unroll
        for (int off = 32; off >= 1; off >>= 1) part += __shfl_xor(part, off);
        const double z2  = part + (double)b2[0];
        const double sig = 1.0 / (1.0 + exp(-z2));
        const double wsf = (double)lengths[b] * sig;   // p - W
        int W0 = (int)rint(wsf);
        if (W0 < 0) W0 = 0;
        if (W0 > SS - WLEN) W0 = SS - WLEN;
        const float pf = (float)(wsf + 64.0);
        if (lane == 0) {
            wsi[b]  = W0;
            pbuf[b] = pf;
            dout[DO_WS + b] = (float)W0;
            dout[DO_WE + b] = (float)(W0 + WLEN);
        }
        #pragma unroll
        for (int q = 0; q < 3; ++q) {
            const int w = lane + 64*q;
            if (w < GW) {
                float g = 0.f;
                if (w < WLEN) {
                    const float d = (float)(W0 + w) - pf;
                    g = expf(d*d * (-1.0f/2048.0f));
                }
                gtab[b*GW + w] = g;
            }
        }
    }
}

// ---------------- L3: score (1024) + last-arriver merge + gemm2c (128, split4) + last-arriver tanh
__global__ __launch_bounds__(256)
void k_final(const double* __restrict__ xa, const double* __restrict__ xb,
             const float* __restrict__ src, const float* __restrict__ Wo,
             const int* __restrict__ wsi, const float* __restrict__ pbuf,
             const int* __restrict__ lengths, const float* __restrict__ gtab,
             const float* __restrict__ opia, const float* __restrict__ opib,
             float* __restrict__ cpart, float* __restrict__ mpart,
             float* __restrict__ lpart, float* __restrict__ spart,
             float* __restrict__ c32, float* __restrict__ opc,
             float* __restrict__ out, int* __restrict__ cnt)
{
    __shared__ __align__(16) float smem[64*130];
    __shared__ int s_last;
    const int blk = blockIdx.x, t = threadIdx.x;
    const int lane = t & 63, wv = t >> 6;

    if (blk < 1024) {
        // ---------- score ----------
        const int b = blk >> 3, wc = blk & 7;
        const int   w0 = wsi[b];
        const int   L  = lengths[b];

        const double* pa = xa + (size_t)b*DSRC + 4*t;
        const double* pb = xb + (size_t)b*DSRC + 4*t;
        const double2 a0 = *reinterpret_cast<const double2*>(pa);
        const double2 a1 = *reinterpret_cast<const double2*>(pa + 2);
        const double2 b0 = *reinterpret_cast<const double2*>(pb);
        const double2 b1 = *reinterpret_cast<const double2*>(pb + 2);
        const float4 x4 = make_float4((float)(a0.x + b0.x), (float)(a0.y + b0.y),
                                      (float)(a1.x + b1.x), (float)(a1.y + b1.y));

        float4 sel[WCH];
        #pragma unroll
        for (int i = 0; i < WCH; ++i) {
            const int w = wc*WCH + i;
            if (w < WLEN) {
                const size_t off = ((size_t)(w0 + w) * BB + b) * DSRC + 4*t;
                sel[i] = *reinterpret_cast<const float4*>(src + off);
            } else sel[i] = make_float4(0.f, 0.f, 0.f, 0.f);
        }

        float w_[32];
        #pragma unroll
        for (int i = 0; i < WCH; ++i)
            w_[i] = fmaf(x4.x, sel[i].x, fmaf(x4.y, sel[i].y, fmaf(x4.z, sel[i].z, x4.w * sel[i].w)));
        #pragma unroll
        for (int i = WCH; i < 32; ++i) w_[i] = 0.f;
        #pragma unroll
        for (int k = 0; k < 5; ++k) {
            const int dist = 1 << k;
            const bool hi = (lane >> k) & 1;
            const int n2 = 32 >> (k + 1);
            #pragma unroll
            for (int i = 0; i < n2; ++i) {
                const float keep = hi ? w_[2*i+1] : w_[2*i];
                const float send = hi ? w_[2*i]   : w_[2*i+1];
                w_[i] = keep + __shfl_xor(send, dist);
            }
        }
        const float tot = w_[0] + __shfl_xor(w_[0], 32);

        float (*red)[4] = (float (*)[4])smem;          // [17][4]
        float* s_sh = smem + WCH*4;                    // [17]
        if (lane < WCH) red[lane][wv] = tot;
        __syncthreads();
        if (t < WCH) {
            const int w = wc*WCH + t;
            float s;
            if (w < WLEN) {
                const float sum = red[t][0] + red[t][1] + red[t][2] + red[t][3];
                const int pos = w0 + w;
                s = (pos >= WW && pos < L + WW) ? sum : 1e-14f;
            } else s = -INFINITY;
            s_sh[t] = s;
        }
        __syncthreads();

        float sv[WCH];
        #pragma unroll
        for (int i = 0; i < WCH; ++i) sv[i] = s_sh[i];
        float m_loc = -INFINITY;
        #pragma unroll
        for (int i = 0; i < WCH; ++i) m_loc = fmaxf(m_loc, sv[i]);
        float l_loc = 0.f;
        float4 c = make_float4(0.f, 0.f, 0.f, 0.f);
        #pragma unroll
        for (int i = 0; i < WCH; ++i) {
            const float e = expf(sv[i] - m_loc);
            l_loc += e;
            const float g = gtab[b*GW + wc*WCH + i];
            const float wt = e * g;
            c.x = fmaf(wt, sel[i].x, c.x);
            c.y = fmaf(wt, sel[i].y, c.y);
            c.z = fmaf(wt, sel[i].z, c.z);
            c.w = fmaf(wt, sel[i].w, c.w);
        }
        *reinterpret_cast<float4*>(cpart + ((size_t)(b*8 + wc))*DSRC + 4*t) = c;
        if (t == 0) { mpart[b*8 + wc] = m_loc; lpart[b*8 + wc] = l_loc; }
        if (t < WCH) spart[(b*8 + wc)*WCH + t] = s_sh[t];

        // ---------- last-arriver merge ----------
        __threadfence();                // release this block's partials
        __syncthreads();
        if (t == 0) s_last = (atomicAdd(&cnt[CNT_B + b], 1) == 7) ? 1 : 0;
        __syncthreads();
        if (s_last) {
            __threadfence();            // acquire siblings' partials
            float* mvs = smem;
            float* lvs = smem + 8;
            if (t < 8) { mvs[t] = mpart[b*8 + t]; lvs[t] = lpart[b*8 + t]; }
            __syncthreads();
            float m = -INFINITY;
            #pragma unroll
            for (int i = 0; i < 8; ++i) m = fmaxf(m, mvs[i]);
            float l = 0.f;
            float fac[8];
            #pragma unroll
            for (int i = 0; i < 8; ++i) { fac[i] = expf(mvs[i] - m); l = fmaf(lvs[i], fac[i], l); }
            const float inv = 1.0f / l;
            float4 cm = make_float4(0.f, 0.f, 0.f, 0.f);
            #pragma unroll
            for (int i = 0; i < 8; ++i) {
                const float4 cp = *reinterpret_cast<const float4*>(cpart + ((size_t)(b*8 + i))*DSRC + 4*t);
                cm.x = fmaf(cp.x, fac[i], cm.x);
                cm.y = fmaf(cp.y, fac[i], cm.y);
                cm.z = fmaf(cp.z, fac[i], cm.z);
                cm.w = fmaf(cp.w, fac[i], cm.w);
            }
            cm.x *= inv; cm.y *= inv; cm.z *= inv; cm.w *= inv;
            *reinterpret_cast<float4*>(c32 + (size_t)b*DSRC + 4*t) = cm;
            if (t < WLEN) {
                const int wcc = t / WCH, i2 = t % WCH;
                const float s = spart[(b*8 + wcc)*WCH + i2];
                const float g = gtab[b*GW + t];
                out[DO_A + b*WLEN + t] = expf(s - m) * inv * g;
            }
            __threadfence();            // release c32
            __syncthreads();
            if (t == 0) atomicAdd(&cnt[CNT_MRG], 1);
        }
    } else {
        // ---------- gemm2c: op c-half = c32 @ Wo[:, :1024]^T, split4, last-arriver tanh ----------
        const int g = blk - 1024;
        const int jb = g & 63, ks = g >> 6;
        const int wvid = __builtin_amdgcn_readfirstlane(t >> 6);
        const int j0 = jb*16 + wvid*4;
        spin_wait(&cnt[CNT_MRG], 128);

        double dac[4][2];
        #pragma unroll
        for (int jj = 0; jj < 4; ++jj) { dac[jj][0] = 0.0; dac[jj][1] = 0.0; }
        gemm_core<256>(t, c32 + ks*256, DSRC, Wo + (size_t)j0*(DIN+DSRC) + ks*256,
                       DIN + DSRC, smem, dac);
        #pragma unroll
        for (int i = 0; i < 2; ++i) {
            const int b = 2*lane + i;
            #pragma unroll
            for (int jj = 0; jj < 4; ++jj)
                opc[((size_t)ks*BB + b)*DOUT + j0 + jj] = (float)dac[jj][i];
        }
        __threadfence();
        __syncthreads();
        if (t == 0) s_last = (atomicAdd(&cnt[CNT_G2 + jb], 1) == 3) ? 1 : 0;
        __syncthreads();
        if (s_last) {
            __threadfence();
            // combine 4 partials + input-half pair, tanh, write stripe [128 b][16 cols]
            #pragma unroll
            for (int q = 0; q < 8; ++q) {
                const int e = t + 256*q;
                const int bb = e & 127, cc = e >> 7;
                const int j = jb*16 + cc;
                float s = 0.f;
                #pragma unroll
                for (int k2 = 0; k2 < 4; ++k2) s += opc[((size_t)k2*BB + bb)*DOUT + j];
                s += opia[(size_t)bb*DOUT + j];
                s += opib[(size_t)bb*DOUT + j];
                out[(size_t)bb*DOUT + j] = tanhf(s);
            }
        }
    }
}

extern "C" void kernel_launch(void* const* d_in, const int* in_sizes, int n_in,
                              void* d_out, int out_size, void* d_ws, size_t ws_size,
                              hipStream_t stream)
{
    const float* input = (const float*)d_in[0];
    const float* src   = (const float*)d_in[1];
    const unsigned char* mask = (const unsigned char*)d_in[2];
    const float* Wi = (const float*)d_in[3];
    const float* Wo = (const float*)d_in[4];
    const float* W1 = (const float*)d_in[5];
    const float* b1 = (const float*)d_in[6];
    const float* W2 = (const float*)d_in[7];
    const float* b2 = (const float*)d_in[8];
    float* out = (float*)d_out;

    if (ws_size < (size_t)WS_NEED) return;

    char* ws = (char*)d_ws;
    int*    cnt     = (int*)   (ws + OFF_CNT);
    int*    wsi     = (int*)   (ws + OFF_WSI);
    float*  pbuf    = (float*) (ws + OFF_P);
    int*    lengths = (int*)   (ws + OFF_LEN);
    float*  gtab    = (float*) (ws + OFF_GTAB);
    double* xa      = (double*)(ws + OFF_XA);
    double* xb      = (double*)(ws + OFF_XB);
    double* z1p     = (double*)(ws + OFF_Z1P);
    float*  opia    = (float*) (ws + OFF_OPIA);
    float*  opib    = (float*) (ws + OFF_OPIB);
    float*  cpart   = (float*) (ws + OFF_CPART);
    float*  mpart   = (float*) (ws + OFF_MPART);
    float*  lpart   = (float*) (ws + OFF_LPART);
    float*  spart   = (float*) (ws + OFF_SPART);
    float*  c32     = (float*) (ws + OFF_C32);
    float*  opc     = (float*) (ws + OFF_OPC);

    // L1: gemm1 (x f64 halves) || gemm2 input-half || lengths || counter init
    k_combo<<<256, 256, 0, stream>>>(input, Wi, Wo, mask, xa, xb, opia, opib, lengths, cnt);
    // L2: fc1 workers + fc2 spinners
    k_fc12<<<160, 256, 0, stream>>>(xa, xb, W1, b1, W2, b2, lengths, z1p,
                                    wsi, pbuf, gtab, out, cnt);
    // L3: score + last-arriver merge + gemm2c + last-arriver tanh epilogue
    k_final<<<1152, 256, 0, stream>>>(xa, xb, src, Wo, wsi, pbuf, lengths, gtab,
                                      opia, opib, cpart, mpart, lpart, spart,
                                      c32, opc, out, cnt);
}

// Round 5
// 110.538 us; speedup vs baseline: 3.4112x; 3.4112x over previous
//
#include <hip/hip_runtime.h>
#include <math.h>

#define BB   128
#define SS   2048
#define DIN  1024
#define DSRC 1024
#define DOUT 1024
#define WW   64
#define WLEN 129
#define HH   512
#define WCH  17     // w-chunk per score block; 8 chunks cover 136 >= 129

// workspace layout (bytes)
#define OFF_WSI   0
#define OFF_P     512
#define OFF_LEN   1024
#define OFF_XP    4096        // double[4][128][1024] = 4 MB
#define OFF_X32   4198400     // float[128][1024]
#define OFF_Z1P   4722688     // double[4][128][512] = 2 MB
#define OFF_C32   6819840     // float[128][1024]
#define OFF_CPART 7344128     // float[128][8][1024] = 4 MB
#define OFF_MPART 11538432
#define OFF_LPART 11542528
#define OFF_SPART 11546624    // float[128][8][17]
#define OFF_OP4   11616256    // float[4][128][1024] = 2 MB (input-half partials)
#define WS_NEED   13713408

// d_out layout (floats)
#define DO_A    (BB*DOUT)        // 131072
#define DO_WS   (DO_A + BB*WLEN) // 147584
#define DO_WE   (DO_WS + BB)     // 147712

// ---------------- 16-col tiled GEMM stage (f32 products, f64 chunk accumulation) ----------------
// R3-proven geometry: NJB = NTOT/16 j-blocks, 4 splits, 8 waves x 2 cols, lanes hold 2 b rows.
template<int NTOT, int KRANGE, bool F64OUT>
__device__ __forceinline__ void gemm16(const int gblk, const int t,
    const float* __restrict__ A, const int lda,
    const float* __restrict__ Wt, const int ldw,
    void* __restrict__ outp, float* __restrict__ alds /* [64][130] */)
{
    constexpr int NJB = NTOT / 16;
    const int jb = gblk % NJB;
    const int ks = gblk / NJB;
    const int lane = t & 63;
    const int wvid = __builtin_amdgcn_readfirstlane(t >> 6);
    const int j0 = jb * 16 + wvid * 2;
    const int k0 = ks * KRANGE;

    double dac[2][2];
    dac[0][0] = 0.0; dac[0][1] = 0.0; dac[1][0] = 0.0; dac[1][1] = 0.0;

    const float* wbase = Wt + (size_t)j0 * ldw;

    for (int kc = 0; kc < KRANGE; kc += 64) {
        const int kg = k0 + kc;
        __syncthreads();
        #pragma unroll
        for (int q = 0; q < 4; ++q) {
            const int f4 = t + 512 * q;
            const int bb = f4 >> 4, c4 = f4 & 15;
            const float4 v = *reinterpret_cast<const float4*>(A + (size_t)bb * lda + kg + c4 * 4);
            alds[(c4*4+0)*130 + bb] = v.x;
            alds[(c4*4+1)*130 + bb] = v.y;
            alds[(c4*4+2)*130 + bb] = v.z;
            alds[(c4*4+3)*130 + bb] = v.w;
        }
        __syncthreads();
        const float* wr = wbase + kg;
        #pragma unroll
        for (int kk16 = 0; kk16 < 64; kk16 += 16) {
            float fa[2][2];
            fa[0][0] = 0.f; fa[0][1] = 0.f; fa[1][0] = 0.f; fa[1][1] = 0.f;
            #pragma unroll
            for (int kk = 0; kk < 16; ++kk) {
                const int k = kk16 + kk;
                const float2 av = *reinterpret_cast<const float2*>(&alds[k*130 + 2*lane]);
                #pragma unroll
                for (int jj = 0; jj < 2; ++jj) {
                    const float wvv = wr[jj*ldw + k];
                    fa[jj][0] = fmaf(wvv, av.x, fa[jj][0]);
                    fa[jj][1] = fmaf(wvv, av.y, fa[jj][1]);
                }
            }
            #pragma unroll
            for (int jj = 0; jj < 2; ++jj) {
                dac[jj][0] += (double)fa[jj][0];
                dac[jj][1] += (double)fa[jj][1];
            }
        }
    }
    #pragma unroll
    for (int i = 0; i < 2; ++i) {
        const int b = 2*lane + i;
        const size_t base = ((size_t)ks * BB + b) * NTOT + j0;
        if constexpr (F64OUT) {
            double* o = (double*)outp;
            o[base + 0] = dac[0][i];
            o[base + 1] = dac[1][i];
        } else {
            float* o = (float*)outp;
            o[base + 0] = (float)dac[0][i];
            o[base + 1] = (float)dac[1][i];
        }
    }
}

// ---------------- L1: combo = gemm1 (256) | gemm2-input-half (256) | lengths (128) ----------------
__global__ __launch_bounds__(512)
void k_combo(const float* __restrict__ input, const float* __restrict__ Wi,
             const float* __restrict__ Wo, const unsigned char* __restrict__ mask,
             double* __restrict__ xp, float* __restrict__ op4, int* __restrict__ lengths)
{
    __shared__ __align__(16) float alds[64*130];
    const int blk = blockIdx.x, t = threadIdx.x;
    if (blk < 256) {
        // x partials = input @ Wi^T  (f64 partials, 4 splits)
        gemm16<1024, 256, true>(blk, t, input, DIN, Wi, DIN, xp, alds);
    } else if (blk < 512) {
        // op4[0..3] = input @ Wo[:,1024:]^T  (independent of everything downstream)
        gemm16<1024, 256, false>(blk - 256, t, input, DIN, Wo + 1024, DIN + DSRC, op4, alds);
    } else {
        const int b = blk - 512;
        const bool is_u8 = (mask[(size_t)SS*BB - 1] != 0);
        int cnt = 0;
        if (is_u8) {
            #pragma unroll
            for (int q = 0; q < 4; ++q)
                cnt += (mask[(size_t)(t + 512*q)*BB + b] != 0) ? 1 : 0;
        } else {
            const int* m32 = (const int*)mask;
            #pragma unroll
            for (int q = 0; q < 4; ++q)
                cnt += (m32[(size_t)(t + 512*q)*BB + b] != 0) ? 1 : 0;
        }
        int* red = (int*)alds;
        red[t] = cnt;
        __syncthreads();
        for (int st = 256; st >= 1; st >>= 1) {
            if (t < st) red[t] += red[t + st];
            __syncthreads();
        }
        if (t == 0) lengths[b] = SS - red[0];
    }
}

// ---------------- L2: reduce xp (4 f64 partials) -> x32 ----------------
__global__ __launch_bounds__(512)
void k_xred(const double* __restrict__ xp, float* __restrict__ x32)
{
    const int i = blockIdx.x * 512 + threadIdx.x;
    double s = 0.0;
    #pragma unroll
    for (int ks = 0; ks < 4; ++ks) s += xp[(size_t)ks * (BB*DSRC) + i];
    x32[i] = (float)s;
}

// ---------------- L3: fc1 partials = x32 @ W1^T ----------------
__global__ __launch_bounds__(512)
void k_fc1(const float* __restrict__ x32, const float* __restrict__ W1, double* __restrict__ z1p)
{
    __shared__ __align__(16) float alds[64*130];
    gemm16<512, 256, true>(blockIdx.x, threadIdx.x, x32, DSRC, W1, DIN, z1p, alds);
}

// ---------------- L4: score with fused fc2 prologue ----------------
// grid (8, 128), 256 threads. All 8 wc-blocks of a b compute identical W0/p deterministically
// (same f64 summation order) — R2-verified splice. lengths comes from L1 (not recomputed).
__global__ __launch_bounds__(256)
void k_score(const float* __restrict__ x32, const float* __restrict__ src,
             const double* __restrict__ z1p, const float* __restrict__ b1,
             const float* __restrict__ W2f, const float* __restrict__ b2,
             const int* __restrict__ lengths,
             int* __restrict__ wsi, float* __restrict__ pbuf,
             float* __restrict__ cpart, float* __restrict__ mpart,
             float* __restrict__ lpart, float* __restrict__ spart,
             float* __restrict__ out)
{
    const int wc = blockIdx.x, b = blockIdx.y;
    const int t = threadIdx.x, lane = t & 63, wv = t >> 6;

    __shared__ double dred[256];
    __shared__ float  red[WCH][4];
    __shared__ float  s_sh[WCH];
    __shared__ int    W0sh;
    __shared__ float  psh;

    const int L = lengths[b];

    // ---- fc2: z1 reduce + tanh + dot(W2) + sigmoid -> W0, p (deterministic, replicated) ----
    {
        double part = 0.0;
        #pragma unroll
        for (int hh = 0; hh < 2; ++hh) {
            const int h = t + 256*hh;
            double z = 0.0;
            #pragma unroll
            for (int ks2 = 0; ks2 < 4; ++ks2) z += z1p[((size_t)ks2*BB + b)*HH + h];
            z += (double)b1[h];
            part += tanh(z) * (double)W2f[h];
        }
        dred[t] = part;
        __syncthreads();
        for (int st = 128; st >= 1; st >>= 1) {
            if (t < st) dred[t] += dred[t + st];
            __syncthreads();
        }
        if (t == 0) {
            const double z2  = dred[0] + (double)b2[0];
            const double sig = 1.0 / (1.0 + exp(-z2));
            const double wsf = (double)L * sig;        // p - W
            int W0 = (int)rint(wsf);
            if (W0 < 0) W0 = 0;
            if (W0 > SS - WLEN) W0 = SS - WLEN;
            W0sh = W0;
            psh  = (float)(wsf + 64.0);
            if (wc == 0) {
                wsi[b]  = W0;
                pbuf[b] = (float)(wsf + 64.0);
                out[DO_WS + b] = (float)W0;
                out[DO_WE + b] = (float)(W0 + WLEN);
            }
        }
        __syncthreads();
    }
    const int   w0 = W0sh;
    const float p  = psh;

    // ---- score body (R3-proven: butterfly reduce) ----
    const float4 x4 = *reinterpret_cast<const float4*>(x32 + b*DSRC + 4*t);

    float4 sel[WCH];
    #pragma unroll
    for (int i = 0; i < WCH; ++i) {
        const int w = wc*WCH + i;
        if (w < WLEN) {
            const size_t off = ((size_t)(w0 + w) * BB + b) * DSRC + 4*t;
            sel[i] = *reinterpret_cast<const float4*>(src + off);
        } else sel[i] = make_float4(0.f, 0.f, 0.f, 0.f);
    }

    float w_[32];
    #pragma unroll
    for (int i = 0; i < WCH; ++i)
        w_[i] = fmaf(x4.x, sel[i].x, fmaf(x4.y, sel[i].y, fmaf(x4.z, sel[i].z, x4.w * sel[i].w)));
    #pragma unroll
    for (int i = WCH; i < 32; ++i) w_[i] = 0.f;

    #pragma unroll
    for (int k = 0; k < 5; ++k) {
        const int dist = 1 << k;
        const bool hi = (lane >> k) & 1;
        const int n2 = 32 >> (k + 1);
        #pragma unroll
        for (int i = 0; i < n2; ++i) {
            const float keep = hi ? w_[2*i+1] : w_[2*i];
            const float send = hi ? w_[2*i]   : w_[2*i+1];
            w_[i] = keep + __shfl_xor(send, dist);
        }
    }
    const float tot = w_[0] + __shfl_xor(w_[0], 32);   // full 64-lane sum of row (lane&31)

    if (lane < WCH) red[lane][wv] = tot;
    __syncthreads();
    if (t < WCH) {
        const int w = wc*WCH + t;
        float s;
        if (w < WLEN) {
            const float sum = red[t][0] + red[t][1] + red[t][2] + red[t][3];
            const int pos = w0 + w;
            s = (pos >= WW && pos < L + WW) ? sum : 1e-14f;
        } else s = -INFINITY;
        s_sh[t] = s;
    }
    __syncthreads();

    float sv[WCH];
    #pragma unroll
    for (int i = 0; i < WCH; ++i) sv[i] = s_sh[i];
    float m_loc = -INFINITY;
    #pragma unroll
    for (int i = 0; i < WCH; ++i) m_loc = fmaxf(m_loc, sv[i]);
    float l_loc = 0.f;
    float4 c = make_float4(0.f, 0.f, 0.f, 0.f);
    #pragma unroll
    for (int i = 0; i < WCH; ++i) {
        const float e = expf(sv[i] - m_loc);       // -inf -> 0 for w >= WLEN
        l_loc += e;
        const int w = wc*WCH + i;
        const float d = (float)(w0 + w) - p;
        const float g = expf(d*d * (-1.0f/2048.0f));
        const float wt = e * g;
        c.x = fmaf(wt, sel[i].x, c.x);
        c.y = fmaf(wt, sel[i].y, c.y);
        c.z = fmaf(wt, sel[i].z, c.z);
        c.w = fmaf(wt, sel[i].w, c.w);
    }
    *reinterpret_cast<float4*>(cpart + ((size_t)(b*8 + wc))*DSRC + 4*t) = c;
    if (t == 0) { mpart[b*8 + wc] = m_loc; lpart[b*8 + wc] = l_loc; }
    if (t < WCH) spart[(b*8 + wc)*WCH + t] = s_sh[t];
}

// ---------------- L5: merge 8 partials per b -> c32 + a output (R0-proven, inline gaussian) -------
__global__ __launch_bounds__(256)
void k_merge(const float* __restrict__ cpart, const float* __restrict__ mpart,
             const float* __restrict__ lpart, const float* __restrict__ spart,
             const int* __restrict__ wsi, const float* __restrict__ pbuf,
             float* __restrict__ c32, float* __restrict__ dout)
{
    const int b = blockIdx.x, t = threadIdx.x;
    __shared__ float mv[8], lv[8];
    if (t < 8) { mv[t] = mpart[b*8 + t]; lv[t] = lpart[b*8 + t]; }
    __syncthreads();
    float m = -INFINITY;
    #pragma unroll
    for (int i = 0; i < 8; ++i) m = fmaxf(m, mv[i]);
    float l = 0.f;
    float fac[8];
    #pragma unroll
    for (int i = 0; i < 8; ++i) { fac[i] = expf(mv[i] - m); l = fmaf(lv[i], fac[i], l); }
    const float inv = 1.0f / l;

    float4 c = make_float4(0.f, 0.f, 0.f, 0.f);
    #pragma unroll
    for (int i = 0; i < 8; ++i) {
        const float4 cp = *reinterpret_cast<const float4*>(cpart + ((size_t)(b*8 + i))*DSRC + 4*t);
        c.x = fmaf(cp.x, fac[i], c.x);
        c.y = fmaf(cp.y, fac[i], c.y);
        c.z = fmaf(cp.z, fac[i], c.z);
        c.w = fmaf(cp.w, fac[i], c.w);
    }
    c.x *= inv; c.y *= inv; c.z *= inv; c.w *= inv;
    *reinterpret_cast<float4*>(c32 + (size_t)b*DSRC + 4*t) = c;

    if (t < WLEN) {
        const int wc = t / WCH, i = t % WCH;
        const float s = spart[(b*8 + wc)*WCH + i];
        const float d = (float)(wsi[b] + t) - pbuf[b];
        const float g = expf(d*d * (-1.0f/2048.0f));
        dout[DO_A + b*WLEN + t] = expf(s - m) * inv * g;
    }
}

// ---------------- L6: full-K output GEMM: out = tanh(c32 @ Wo_c^T + input-half partials) ----------
// 128 blocks x 256 thr (4 waves x 2 cols, lanes hold 2 rows). K=1024 in registers, chunk prefetch.
__global__ __launch_bounds__(256)
void k_gemm2cf(const float* __restrict__ c32, const float* __restrict__ Wo,
               const float* __restrict__ op4, float* __restrict__ out)
{
    __shared__ __align__(16) float alds[64*130];
    const int jb = blockIdx.x;           // 0..127
    const int t = threadIdx.x, lane = t & 63;
    const int wvid = __builtin_amdgcn_readfirstlane(t >> 6);
    const int j0 = jb * 8 + wvid * 2;
    const float* wbase = Wo + (size_t)j0 * (DIN + DSRC);   // c-half: cols 0..1023

    double dac[2][2];
    dac[0][0] = 0.0; dac[0][1] = 0.0; dac[1][0] = 0.0; dac[1][1] = 0.0;

    float4 pf[8];
    #pragma unroll
    for (int q = 0; q < 8; ++q) {
        const int f4 = t + 256*q;
        const int bb = f4 >> 4, c4 = f4 & 15;
        pf[q] = *reinterpret_cast<const float4*>(c32 + (size_t)bb*DSRC + c4*4);
    }
    for (int c = 0; c < 16; ++c) {
        __syncthreads();
        #pragma unroll
        for (int q = 0; q < 8; ++q) {
            const int f4 = t + 256*q;
            const int bb = f4 >> 4, c4 = f4 & 15;
            alds[(c4*4+0)*130 + bb] = pf[q].x;
            alds[(c4*4+1)*130 + bb] = pf[q].y;
            alds[(c4*4+2)*130 + bb] = pf[q].z;
            alds[(c4*4+3)*130 + bb] = pf[q].w;
        }
        __syncthreads();
        if (c + 1 < 16) {
            #pragma unroll
            for (int q = 0; q < 8; ++q) {
                const int f4 = t + 256*q;
                const int bb = f4 >> 4, c4 = f4 & 15;
                pf[q] = *reinterpret_cast<const float4*>(c32 + (size_t)bb*DSRC + (c+1)*64 + c4*4);
            }
        }
        const float* wr = wbase + c*64;
        #pragma unroll
        for (int kk16 = 0; kk16 < 64; kk16 += 16) {
            float fa[2][2];
            fa[0][0] = 0.f; fa[0][1] = 0.f; fa[1][0] = 0.f; fa[1][1] = 0.f;
            #pragma unroll
            for (int kk = 0; kk < 16; ++kk) {
                const int k = kk16 + kk;
                const float2 av = *reinterpret_cast<const float2*>(&alds[k*130 + 2*lane]);
                #pragma unroll
                for (int jj = 0; jj < 2; ++jj) {
                    const float wvv = wr[(size_t)jj*(DIN+DSRC) + k];
                    fa[jj][0] = fmaf(wvv, av.x, fa[jj][0]);
                    fa[jj][1] = fmaf(wvv, av.y, fa[jj][1]);
                }
            }
            #pragma unroll
            for (int jj = 0; jj < 2; ++jj) {
                dac[jj][0] += (double)fa[jj][0];
                dac[jj][1] += (double)fa[jj][1];
            }
        }
    }
    #pragma unroll
    for (int i = 0; i < 2; ++i) {
        const int b = 2*lane + i;
        #pragma unroll
        for (int jj = 0; jj < 2; ++jj) {
            const int j = j0 + jj;
            float s = (float)dac[jj][i];
            #pragma unroll
            for (int ks2 = 0; ks2 < 4; ++ks2)
                s += op4[((size_t)ks2*BB + b)*DOUT + j];
            out[(size_t)b*DOUT + j] = tanhf(s);
        }
    }
}

extern "C" void kernel_launch(void* const* d_in, const int* in_sizes, int n_in,
                              void* d_out, int out_size, void* d_ws, size_t ws_size,
                              hipStream_t stream)
{
    const float* input = (const float*)d_in[0];
    const float* src   = (const float*)d_in[1];
    const unsigned char* mask = (const unsigned char*)d_in[2];
    const float* Wi = (const float*)d_in[3];
    const float* Wo = (const float*)d_in[4];
    const float* W1 = (const float*)d_in[5];
    const float* b1 = (const float*)d_in[6];
    const float* W2 = (const float*)d_in[7];
    const float* b2 = (const float*)d_in[8];
    float* out = (float*)d_out;

    if (ws_size < (size_t)WS_NEED) return;

    char* ws = (char*)d_ws;
    int*    wsi     = (int*)   (ws + OFF_WSI);
    float*  pbuf    = (float*) (ws + OFF_P);
    int*    lengths = (int*)   (ws + OFF_LEN);
    double* xp      = (double*)(ws + OFF_XP);
    float*  x32     = (float*) (ws + OFF_X32);
    double* z1p     = (double*)(ws + OFF_Z1P);
    float*  c32     = (float*) (ws + OFF_C32);
    float*  cpart   = (float*) (ws + OFF_CPART);
    float*  mpart   = (float*) (ws + OFF_MPART);
    float*  lpart   = (float*) (ws + OFF_LPART);
    float*  spart   = (float*) (ws + OFF_SPART);
    float*  op4     = (float*) (ws + OFF_OP4);

    // L1: gemm1 || gemm2-input-half || lengths  (all mutually independent)
    k_combo<<<640, 512, 0, stream>>>(input, Wi, Wo, mask, xp, op4, lengths);
    // L2: x32 = f64-reduce(xp)
    k_xred<<<256, 512, 0, stream>>>(xp, x32);
    // L3: z1 partials = x32 @ W1^T
    k_fc1<<<128, 512, 0, stream>>>(x32, W1, z1p);
    // L4: score with fused fc2 prologue (writes wsi/pbuf/ws/we from wc==0 blocks)
    k_score<<<dim3(8,128), 256, 0, stream>>>(x32, src, z1p, b1, W2, b2, lengths,
                                             wsi, pbuf, cpart, mpart, lpart, spart, out);
    // L5: merge partials -> c32 + a
    k_merge<<<128, 256, 0, stream>>>(cpart, mpart, lpart, spart, wsi, pbuf, c32, out);
    // L6: out = tanh(c32 @ Wo_c^T + input-half)   (full-K, no split, no outred)
    k_gemm2cf<<<128, 256, 0, stream>>>(c32, Wo, op4, out);
}

// Round 6
// 95.009 us; speedup vs baseline: 3.9688x; 1.1634x over previous
//
#include <hip/hip_runtime.h>
#include <math.h>

#define BB   128
#define SS   2048
#define DIN  1024
#define DSRC 1024
#define DOUT 1024
#define WW   64
#define WLEN 129
#define HH   512
#define WCH  17     // w-chunk per score block; 8 chunks cover 136 >= 129

// workspace layout (bytes)
#define OFF_WSI   0
#define OFF_P     512
#define OFF_LEN   1024
#define OFF_XP    4096        // double[4][128][1024] = 4 MB
#define OFF_Z1P   4198400     // double[4][128][512] = 2 MB
#define OFF_C32   6295552     // float[128][1024]
#define OFF_CPART 6819840     // float[128][8][1024] = 4 MB
#define OFF_MPART 11014144
#define OFF_LPART 11018240
#define OFF_SPART 11022336    // float[128][8][17]
#define OFF_OP    11091968    // float[8][128][1024] = 4 MB ([0..3]=c-half, [4..7]=input-half)
#define WS_NEED   15286272

// d_out layout (floats)
#define DO_A    (BB*DOUT)        // 131072
#define DO_WS   (DO_A + BB*WLEN) // 147584
#define DO_WE   (DO_WS + BB)     // 147712

// ---------------- 16-col tiled GEMM stage (f32 products, f64 chunk accumulation) ----------------
// R3-proven geometry: NJB = NTOT/16 j-blocks, 4 splits, 8 waves x 2 cols, lanes hold 2 b rows.
template<int NTOT, int KRANGE, bool F64OUT>
__device__ __forceinline__ void gemm16(const int gblk, const int t,
    const float* __restrict__ A, const int lda,
    const float* __restrict__ Wt, const int ldw,
    void* __restrict__ outp, float* __restrict__ alds /* [64][130] */)
{
    constexpr int NJB = NTOT / 16;
    const int jb = gblk % NJB;
    const int ks = gblk / NJB;
    const int lane = t & 63;
    const int wvid = __builtin_amdgcn_readfirstlane(t >> 6);
    const int j0 = jb * 16 + wvid * 2;
    const int k0 = ks * KRANGE;

    double dac[2][2];
    dac[0][0] = 0.0; dac[0][1] = 0.0; dac[1][0] = 0.0; dac[1][1] = 0.0;

    const float* wbase = Wt + (size_t)j0 * ldw;

    for (int kc = 0; kc < KRANGE; kc += 64) {
        const int kg = k0 + kc;
        __syncthreads();
        #pragma unroll
        for (int q = 0; q < 4; ++q) {
            const int f4 = t + 512 * q;
            const int bb = f4 >> 4, c4 = f4 & 15;
            const float4 v = *reinterpret_cast<const float4*>(A + (size_t)bb * lda + kg + c4 * 4);
            alds[(c4*4+0)*130 + bb] = v.x;
            alds[(c4*4+1)*130 + bb] = v.y;
            alds[(c4*4+2)*130 + bb] = v.z;
            alds[(c4*4+3)*130 + bb] = v.w;
        }
        __syncthreads();
        const float* wr = wbase + kg;
        #pragma unroll
        for (int kk16 = 0; kk16 < 64; kk16 += 16) {
            float fa[2][2];
            fa[0][0] = 0.f; fa[0][1] = 0.f; fa[1][0] = 0.f; fa[1][1] = 0.f;
            #pragma unroll
            for (int kk = 0; kk < 16; ++kk) {
                const int k = kk16 + kk;
                const float2 av = *reinterpret_cast<const float2*>(&alds[k*130 + 2*lane]);
                #pragma unroll
                for (int jj = 0; jj < 2; ++jj) {
                    const float wvv = wr[jj*ldw + k];
                    fa[jj][0] = fmaf(wvv, av.x, fa[jj][0]);
                    fa[jj][1] = fmaf(wvv, av.y, fa[jj][1]);
                }
            }
            #pragma unroll
            for (int jj = 0; jj < 2; ++jj) {
                dac[jj][0] += (double)fa[jj][0];
                dac[jj][1] += (double)fa[jj][1];
            }
        }
    }
    #pragma unroll
    for (int i = 0; i < 2; ++i) {
        const int b = 2*lane + i;
        const size_t base = ((size_t)ks * BB + b) * NTOT + j0;
        if constexpr (F64OUT) {
            double* o = (double*)outp;
            o[base + 0] = dac[0][i];
            o[base + 1] = dac[1][i];
        } else {
            float* o = (float*)outp;
            o[base + 0] = (float)dac[0][i];
            o[base + 1] = (float)dac[1][i];
        }
    }
}

// ---------------- L1: combo = gemm1 (256) | gemm2-input-half (256) | lengths (128) ----------------
__global__ __launch_bounds__(512)
void k_combo(const float* __restrict__ input, const float* __restrict__ Wi,
             const float* __restrict__ Wo, const unsigned char* __restrict__ mask,
             double* __restrict__ xp, float* __restrict__ op4, int* __restrict__ lengths)
{
    __shared__ __align__(16) float alds[64*130];
    const int blk = blockIdx.x, t = threadIdx.x;
    if (blk < 256) {
        // x partials = input @ Wi^T  (f64 partials, 4 splits)
        gemm16<1024, 256, true>(blk, t, input, DIN, Wi, DIN, xp, alds);
    } else if (blk < 512) {
        // op[4..7] = input @ Wo[:,1024:]^T  (independent of everything downstream)
        gemm16<1024, 256, false>(blk - 256, t, input, DIN, Wo + 1024, DIN + DSRC, op4, alds);
    } else {
        const int b = blk - 512;
        const bool is_u8 = (mask[(size_t)SS*BB - 1] != 0);
        int cnt = 0;
        if (is_u8) {
            #pragma unroll
            for (int q = 0; q < 4; ++q)
                cnt += (mask[(size_t)(t + 512*q)*BB + b] != 0) ? 1 : 0;
        } else {
            const int* m32 = (const int*)mask;
            #pragma unroll
            for (int q = 0; q < 4; ++q)
                cnt += (m32[(size_t)(t + 512*q)*BB + b] != 0) ? 1 : 0;
        }
        int* red = (int*)alds;
        red[t] = cnt;
        __syncthreads();
        for (int st = 256; st >= 1; st >>= 1) {
            if (t < st) red[t] += red[t + st];
            __syncthreads();
        }
        if (t == 0) lengths[b] = SS - red[0];
    }
}

// ---------------- L2: fc1 staged directly from xp (inline ks-ascending f64 reduce) ----------------
// 64 blocks (16 j-blocks x 32 cols, 4 K-splits), 512 thr = 8 waves x 4 cols, lanes hold 2 rows.
// Staged values (float)(xp0+xp1+xp2+xp3) are bit-identical to R3's x32; K-chunk structure identical
// -> z1p bit-identical to R3.
__global__ __launch_bounds__(512)
void k_fc1x(const double* __restrict__ xp, const float* __restrict__ W1, double* __restrict__ z1p)
{
    __shared__ __align__(16) float alds[64*130];
    const int blk = blockIdx.x, t = threadIdx.x;
    const int jb = blk & 15;
    const int ks = blk >> 4;
    const int lane = t & 63;
    const int wvid = __builtin_amdgcn_readfirstlane(t >> 6);
    const int j0 = jb * 32 + wvid * 4;
    const int k0 = ks * 256;

    double dac[4][2];
    #pragma unroll
    for (int jj = 0; jj < 4; ++jj) { dac[jj][0] = 0.0; dac[jj][1] = 0.0; }

    const float* wbase = W1 + (size_t)j0 * DIN;

    for (int kc = 0; kc < 256; kc += 64) {
        const int kg = k0 + kc;
        __syncthreads();
        #pragma unroll
        for (int q = 0; q < 4; ++q) {
            const int f4 = t + 512 * q;
            const int bb = f4 >> 4, c4 = f4 & 15;
            const double* base = xp + (size_t)bb * DSRC + kg + c4 * 4;
            double s0 = 0.0, s1 = 0.0, s2 = 0.0, s3 = 0.0;
            #pragma unroll
            for (int ks2 = 0; ks2 < 4; ++ks2) {
                const double* p2 = base + (size_t)ks2 * (BB*DSRC);
                const double2 a = *reinterpret_cast<const double2*>(p2);
                const double2 c = *reinterpret_cast<const double2*>(p2 + 2);
                s0 += a.x; s1 += a.y; s2 += c.x; s3 += c.y;
            }
            alds[(c4*4+0)*130 + bb] = (float)s0;
            alds[(c4*4+1)*130 + bb] = (float)s1;
            alds[(c4*4+2)*130 + bb] = (float)s2;
            alds[(c4*4+3)*130 + bb] = (float)s3;
        }
        __syncthreads();
        const float* wr = wbase + kg;
        #pragma unroll
        for (int kk16 = 0; kk16 < 64; kk16 += 16) {
            float fa[4][2];
            #pragma unroll
            for (int jj = 0; jj < 4; ++jj) { fa[jj][0] = 0.f; fa[jj][1] = 0.f; }
            #pragma unroll
            for (int kk = 0; kk < 16; ++kk) {
                const int k = kk16 + kk;
                const float2 av = *reinterpret_cast<const float2*>(&alds[k*130 + 2*lane]);
                #pragma unroll
                for (int jj = 0; jj < 4; ++jj) {
                    const float wvv = wr[jj*DIN + k];
                    fa[jj][0] = fmaf(wvv, av.x, fa[jj][0]);
                    fa[jj][1] = fmaf(wvv, av.y, fa[jj][1]);
                }
            }
            #pragma unroll
            for (int jj = 0; jj < 4; ++jj) {
                dac[jj][0] += (double)fa[jj][0];
                dac[jj][1] += (double)fa[jj][1];
            }
        }
    }
    #pragma unroll
    for (int i = 0; i < 2; ++i) {
        const int b = 2*lane + i;
        const size_t base = ((size_t)ks * BB + b) * HH + j0;
        #pragma unroll
        for (int jj = 0; jj < 4; ++jj) z1p[base + jj] = dac[jj][i];
    }
}

// ---------------- L3: fc2: z1 reduce + tanh + dot(W2) + sigmoid -> W0, p, ws/we ----------------
__global__ __launch_bounds__(64)
void k_fc2(const double* __restrict__ z1p, const float* __restrict__ b1,
           const float* __restrict__ W2f, const float* __restrict__ b2,
           const int* __restrict__ lengths, int* __restrict__ wsi,
           float* __restrict__ pbuf, float* __restrict__ dout)
{
    const int b = blockIdx.x, lane = threadIdx.x;
    double part = 0.0;
    #pragma unroll
    for (int q = 0; q < 8; ++q) {
        const int h = lane + 64*q;
        double z = 0.0;
        #pragma unroll
        for (int ks = 0; ks < 4; ++ks) z += z1p[((size_t)ks*BB + b)*HH + h];
        z += (double)b1[h];
        part += tanh(z) * (double)W2f[h];
    }
    #pragma unroll
    for (int off = 32; off >= 1; off >>= 1) part += __shfl_xor(part, off);
    if (lane == 0) {
        const double z2  = part + (double)b2[0];
        const double sig = 1.0 / (1.0 + exp(-z2));
        const double wsf = (double)lengths[b] * sig;   // p - W
        int W0 = (int)rint(wsf);
        if (W0 < 0) W0 = 0;
        if (W0 > SS - WLEN) W0 = SS - WLEN;
        wsi[b]  = W0;
        pbuf[b] = (float)(wsf + 64.0);
        dout[DO_WS + b] = (float)W0;
        dout[DO_WE + b] = (float)(W0 + WLEN);
    }
}

// ---------------- L4: per-(b, w-chunk) scores + local softmax + partial c ----------------
// grid (8, 128), 256 threads. x4 reduced inline from xp (bit-identical to R3's x32 values).
__global__ __launch_bounds__(256)
void k_score(const double* __restrict__ xp, const float* __restrict__ src,
             const int* __restrict__ wsi, const float* __restrict__ pbuf,
             const int* __restrict__ lengths,
             float* __restrict__ cpart, float* __restrict__ mpart,
             float* __restrict__ lpart, float* __restrict__ spart)
{
    const int wc = blockIdx.x, b = blockIdx.y;
    const int t = threadIdx.x, lane = t & 63, wv = t >> 6;
    const int   w0 = wsi[b];
    const float p  = pbuf[b];
    const int   L  = lengths[b];

    // x4 = (float) sum_ks xp  (same ks-ascending f64 order + f32 cast as R3's x32)
    float4 x4;
    {
        const double* base = xp + (size_t)b * DSRC + 4 * t;
        double s0 = 0.0, s1 = 0.0, s2 = 0.0, s3 = 0.0;
        #pragma unroll
        for (int ks2 = 0; ks2 < 4; ++ks2) {
            const double* p2 = base + (size_t)ks2 * (BB*DSRC);
            const double2 a = *reinterpret_cast<const double2*>(p2);
            const double2 c = *reinterpret_cast<const double2*>(p2 + 2);
            s0 += a.x; s1 += a.y; s2 += c.x; s3 += c.y;
        }
        x4 = make_float4((float)s0, (float)s1, (float)s2, (float)s3);
    }

    float4 sel[WCH];
    #pragma unroll
    for (int i = 0; i < WCH; ++i) {
        const int w = wc*WCH + i;
        if (w < WLEN) {
            const size_t off = ((size_t)(w0 + w) * BB + b) * DSRC + 4*t;
            sel[i] = *reinterpret_cast<const float4*>(src + off);
        } else sel[i] = make_float4(0.f, 0.f, 0.f, 0.f);
    }

    float w_[32];
    #pragma unroll
    for (int i = 0; i < WCH; ++i)
        w_[i] = fmaf(x4.x, sel[i].x, fmaf(x4.y, sel[i].y, fmaf(x4.z, sel[i].z, x4.w * sel[i].w)));
    #pragma unroll
    for (int i = WCH; i < 32; ++i) w_[i] = 0.f;

    #pragma unroll
    for (int k = 0; k < 5; ++k) {
        const int dist = 1 << k;
        const bool hi = (lane >> k) & 1;
        const int n2 = 32 >> (k + 1);
        #pragma unroll
        for (int i = 0; i < n2; ++i) {
            const float keep = hi ? w_[2*i+1] : w_[2*i];
            const float send = hi ? w_[2*i]   : w_[2*i+1];
            w_[i] = keep + __shfl_xor(send, dist);
        }
    }
    const float tot = w_[0] + __shfl_xor(w_[0], 32);   // full 64-lane sum of row (lane&31)

    __shared__ float red[WCH][4];
    __shared__ float s_sh[WCH];
    if (lane < WCH) red[lane][wv] = tot;
    __syncthreads();
    if (t < WCH) {
        const int w = wc*WCH + t;
        float s;
        if (w < WLEN) {
            const float sum = red[t][0] + red[t][1] + red[t][2] + red[t][3];
            const int pos = w0 + w;
            s = (pos >= WW && pos < L + WW) ? sum : 1e-14f;
        } else s = -INFINITY;
        s_sh[t] = s;
    }
    __syncthreads();

    float sv[WCH];
    #pragma unroll
    for (int i = 0; i < WCH; ++i) sv[i] = s_sh[i];
    float m_loc = -INFINITY;
    #pragma unroll
    for (int i = 0; i < WCH; ++i) m_loc = fmaxf(m_loc, sv[i]);
    float l_loc = 0.f;
    float4 c = make_float4(0.f, 0.f, 0.f, 0.f);
    #pragma unroll
    for (int i = 0; i < WCH; ++i) {
        const float e = expf(sv[i] - m_loc);       // -inf -> 0 for w >= WLEN
        l_loc += e;
        const int w = wc*WCH + i;
        const float d = (float)(w0 + w) - p;
        const float g = expf(d*d * (-1.0f/2048.0f));
        const float wt = e * g;
        c.x = fmaf(wt, sel[i].x, c.x);
        c.y = fmaf(wt, sel[i].y, c.y);
        c.z = fmaf(wt, sel[i].z, c.z);
        c.w = fmaf(wt, sel[i].w, c.w);
    }
    *reinterpret_cast<float4*>(cpart + ((size_t)(b*8 + wc))*DSRC + 4*t) = c;
    if (t == 0) { mpart[b*8 + wc] = m_loc; lpart[b*8 + wc] = l_loc; }
    if (t < WCH) spart[(b*8 + wc)*WCH + t] = s_sh[t];
}

// ---------------- L5: merge 8 partials per b -> c32 + a output ----------------
__global__ __launch_bounds__(256)
void k_merge(const float* __restrict__ cpart, const float* __restrict__ mpart,
             const float* __restrict__ lpart, const float* __restrict__ spart,
             const int* __restrict__ wsi, const float* __restrict__ pbuf,
             float* __restrict__ c32, float* __restrict__ dout)
{
    const int b = blockIdx.x, t = threadIdx.x;
    __shared__ float mv[8], lv[8];
    if (t < 8) { mv[t] = mpart[b*8 + t]; lv[t] = lpart[b*8 + t]; }
    __syncthreads();
    float m = -INFINITY;
    #pragma unroll
    for (int i = 0; i < 8; ++i) m = fmaxf(m, mv[i]);
    float l = 0.f;
    float fac[8];
    #pragma unroll
    for (int i = 0; i < 8; ++i) { fac[i] = expf(mv[i] - m); l = fmaf(lv[i], fac[i], l); }
    const float inv = 1.0f / l;

    float4 c = make_float4(0.f, 0.f, 0.f, 0.f);
    #pragma unroll
    for (int i = 0; i < 8; ++i) {
        const float4 cp = *reinterpret_cast<const float4*>(cpart + ((size_t)(b*8 + i))*DSRC + 4*t);
        c.x = fmaf(cp.x, fac[i], c.x);
        c.y = fmaf(cp.y, fac[i], c.y);
        c.z = fmaf(cp.z, fac[i], c.z);
        c.w = fmaf(cp.w, fac[i], c.w);
    }
    c.x *= inv; c.y *= inv; c.z *= inv; c.w *= inv;
    *reinterpret_cast<float4*>(c32 + (size_t)b*DSRC + 4*t) = c;

    if (t < WLEN) {
        const int wc = t / WCH, i = t % WCH;
        const float s = spart[(b*8 + wc)*WCH + i];
        const float d = (float)(wsi[b] + t) - pbuf[b];
        const float g = expf(d*d * (-1.0f/2048.0f));
        dout[DO_A + b*WLEN + t] = expf(s - m) * inv * g;
    }
}

// ---------------- L6: op[0..3] = c32 @ Wo[:, :1024]^T ----------------
__global__ __launch_bounds__(512)
void k_gemm2c(const float* __restrict__ c32, const float* __restrict__ Wo, float* __restrict__ op)
{
    __shared__ __align__(16) float alds[64*130];
    gemm16<1024, 256, false>(blockIdx.x, threadIdx.x, c32, DSRC, Wo, DIN + DSRC, op, alds);
}

// ---------------- L7: reduce 8 op partials + tanh -> out ----------------
__global__ __launch_bounds__(512)
void k_outred(const float* __restrict__ op, float* __restrict__ dout)
{
    const int i = blockIdx.x * 512 + threadIdx.x;
    float s = 0.f;
    #pragma unroll
    for (int ks = 0; ks < 8; ++ks) s += op[(size_t)ks * (BB*DOUT) + i];
    dout[i] = tanhf(s);
}

extern "C" void kernel_launch(void* const* d_in, const int* in_sizes, int n_in,
                              void* d_out, int out_size, void* d_ws, size_t ws_size,
                              hipStream_t stream)
{
    const float* input = (const float*)d_in[0];
    const float* src   = (const float*)d_in[1];
    const unsigned char* mask = (const unsigned char*)d_in[2];
    const float* Wi = (const float*)d_in[3];
    const float* Wo = (const float*)d_in[4];
    const float* W1 = (const float*)d_in[5];
    const float* b1 = (const float*)d_in[6];
    const float* W2 = (const float*)d_in[7];
    const float* b2 = (const float*)d_in[8];
    float* out = (float*)d_out;

    if (ws_size < (size_t)WS_NEED) return;

    char* ws = (char*)d_ws;
    int*    wsi     = (int*)   (ws + OFF_WSI);
    float*  pbuf    = (float*) (ws + OFF_P);
    int*    lengths = (int*)   (ws + OFF_LEN);
    double* xp      = (double*)(ws + OFF_XP);
    double* z1p     = (double*)(ws + OFF_Z1P);
    float*  c32     = (float*) (ws + OFF_C32);
    float*  cpart   = (float*) (ws + OFF_CPART);
    float*  mpart   = (float*) (ws + OFF_MPART);
    float*  lpart   = (float*) (ws + OFF_LPART);
    float*  spart   = (float*) (ws + OFF_SPART);
    float*  op      = (float*) (ws + OFF_OP);

    // L1: gemm1 (xp f64 partials) || gemm2-input-half (op[4..7]) || lengths
    k_combo<<<640, 512, 0, stream>>>(input, Wi, Wo, mask, xp, op + 4*(size_t)BB*DOUT, lengths);
    // L2: z1 partials = x @ W1^T, staging A from xp with inline f64 reduce (xred eliminated)
    k_fc1x<<<64, 512, 0, stream>>>(xp, W1, z1p);
    // L3: fc2 -> W0/p/ws/we
    k_fc2<<<128, 64, 0, stream>>>(z1p, b1, W2, b2, lengths, wsi, pbuf, out);
    // L4: scores + local softmax + partial c (x4 reduced inline from xp)
    k_score<<<dim3(8,128), 256, 0, stream>>>(xp, src, wsi, pbuf, lengths,
                                             cpart, mpart, lpart, spart);
    // L5: merge partials -> c32 + a
    k_merge<<<128, 256, 0, stream>>>(cpart, mpart, lpart, spart, wsi, pbuf, c32, out);
    // L6: op[0..3] = c32 @ Wo_c^T
    k_gemm2c<<<256, 512, 0, stream>>>(c32, Wo, op);
    // L7: out = tanh(sum op)
    k_outred<<<256, 512, 0, stream>>>(op, out);
}